// Round 5
// baseline (293.427 us; speedup 1.0000x reference)
//
#include <hip/hip_runtime.h>
#include <hip/hip_bf16.h>

// (B,N,D) = (4,4096,256) fp32 in/out. MFMA fp16-split pipeline:
//  proj (3-term fp16 split MFMA) -> qh,ql (Q pre-scaled by log2e), kh, v
//  transpose v -> vT[d][n]
//  attn: flash, 32-row q-tiles, 4 waves (key-split QK^T, col-split PV),
//        per-wave local softmax + consumer-side correction (1 barrier/iter),
//        P exchanged as prebuilt MFMA A-fragments (conflict-free LDS),
//        Q-lo in LDS frags, V prefetched to regs before the barrier.

#define SEQ   4096
#define DIM   256
#define LOG2E 1.4426950408889634f

typedef _Float16 f16;
typedef __attribute__((ext_vector_type(8)))  f16    f16x8;
typedef __attribute__((ext_vector_type(2)))  __fp16 pk16x2;   // cvt_pkrtz native type
typedef __attribute__((ext_vector_type(16))) float  f32x16;

// ---------------------------------------------------------------------------
// Projection: Y[m][e] = sum_d X[m][d]*W[e][d] + b[e], scaled, fp16 hi(+lo) out.
// (unchanged — verified rounds 3/4)
// ---------------------------------------------------------------------------
__global__ __launch_bounds__(256) void proj_mfma(
    const float* __restrict__ X, const float* __restrict__ W,
    const float* __restrict__ bias, f16* __restrict__ outH,
    f16* __restrict__ outL, float scale)
{
    const int w = threadIdx.x >> 6, lane = threadIdx.x & 63;
    const int col = lane & 31, hi = lane >> 5;
    const int m0 = blockIdx.x * 64 + (w & 1) * 32;
    const int e0 = (w >> 1) * 128;

    f32x16 acc[4] = {};
    for (int s = 0; s < 16; ++s) {
        const float* xp = X + (size_t)(m0 + col) * DIM + s * 16 + 8 * hi;
        float xv[8];
        *(float4*)&xv[0] = *(const float4*)xp;
        *(float4*)&xv[4] = *(const float4*)(xp + 4);
        f16x8 xh, xl;
        #pragma unroll
        for (int i = 0; i < 8; ++i) {
            xh[i] = (f16)xv[i];
            xl[i] = (f16)(xv[i] - (float)xh[i]);
        }
        #pragma unroll
        for (int c = 0; c < 4; ++c) {
            const float* wp = W + (size_t)(e0 + c * 32 + col) * DIM + s * 16 + 8 * hi;
            float wv[8];
            *(float4*)&wv[0] = *(const float4*)wp;
            *(float4*)&wv[4] = *(const float4*)(wp + 4);
            f16x8 wh, wl;
            #pragma unroll
            for (int i = 0; i < 8; ++i) {
                wh[i] = (f16)wv[i];
                wl[i] = (f16)(wv[i] - (float)wh[i]);
            }
            acc[c] = __builtin_amdgcn_mfma_f32_32x32x16_f16(xh, wh, acc[c], 0, 0, 0);
            acc[c] = __builtin_amdgcn_mfma_f32_32x32x16_f16(xl, wh, acc[c], 0, 0, 0);
            acc[c] = __builtin_amdgcn_mfma_f32_32x32x16_f16(xh, wl, acc[c], 0, 0, 0);
        }
    }
    #pragma unroll
    for (int c = 0; c < 4; ++c) {
        const int e = e0 + c * 32 + col;
        const float b = bias[e];
        #pragma unroll
        for (int r = 0; r < 16; ++r) {
            const int m = m0 + (r & 3) + 8 * (r >> 2) + 4 * hi;
            const float y = (acc[c][r] + b) * scale;
            const f16 yh = (f16)y;
            const size_t o = (size_t)m * DIM + e;
            outH[o] = yh;
            if (outL) outL[o] = (f16)(y - (float)yh);
        }
    }
}

// ---------------------------------------------------------------------------
// v (fp16 [N][256] per batch) -> vT (fp16 [256][N] per batch)  (unchanged)
// ---------------------------------------------------------------------------
__global__ void transpose_v(const f16* __restrict__ v, f16* __restrict__ vT)
{
    __shared__ f16 tile[32][33];
    const size_t pp = (size_t)SEQ * DIM;
    const f16* vb = v + blockIdx.z * pp;
    f16* vTb = vT + blockIdx.z * pp;
    const int n0 = blockIdx.x * 32, e0 = blockIdx.y * 32;
    #pragma unroll
    for (int r = 0; r < 4; ++r)
        tile[threadIdx.y + 8 * r][threadIdx.x] =
            vb[(size_t)(n0 + threadIdx.y + 8 * r) * DIM + e0 + threadIdx.x];
    __syncthreads();
    #pragma unroll
    for (int r = 0; r < 4; ++r)
        vTb[(size_t)(e0 + threadIdx.y + 8 * r) * SEQ + n0 + threadIdx.x] =
            tile[threadIdx.x][threadIdx.y + 8 * r];
}

// ---------------------------------------------------------------------------
// Flash attention. One block = 32 q-rows, 4 waves. 128-key iterations:
//   wave w: QK^T for keys [j0+32w, j0+32w+32)  (K direct from global,
//           Q-hi in regs, Q-lo from LDS frags)
//   per-wave local softmax (own max) -> A-frags (cvt_pk + shfl_xor(32))
//   -> conflict-free LDS frag store; ONE barrier; consumers apply
//   corr_w = 2^(pmax_w - m_run) to A-frags (defer-max window 8 nats).
//   PV: wave w owns output cols [64w, 64w+64); V prefetched pre-barrier.
// ---------------------------------------------------------------------------
__global__ __launch_bounds__(256, 2) void attn_flash(
    const f16* __restrict__ qh, const f16* __restrict__ ql,
    const f16* __restrict__ kh, const f16* __restrict__ vT,
    float* __restrict__ out, int nbatch)
{
    int qt, b;
    if (nbatch == 4) {
        const int lin = blockIdx.x;              // 512 blocks
        const int x = lin & 7;                   // XCD
        b = x >> 1;                              // 2 XCDs per batch
        const int k = lin >> 3;                  // [0,64) within XCD
        const int j = (k & 1) ? (63 - (k >> 1)) : (k >> 1);   // zig-zag balance
        qt = 2 * j + (x & 1);
    } else {
        qt = blockIdx.x; b = 0;
    }
    const size_t pp = (size_t)SEQ * DIM;
    const f16* qhb = qh + b * pp;
    const f16* qlb = ql + b * pp;
    const f16* khb = kh + b * pp;
    const f16* vTb = vT + b * pp;                // [256][4096]
    float* outb = out + b * pp;

    const int wid = threadIdx.x >> 6, lane = threadIdx.x & 63;
    const int col = lane & 31, hi = lane >> 5;
    const int q0 = qt * 32;
    const int qend = q0 + 32;
    const int niter = (qend + 127) >> 7;

    __shared__ uint4 Pfrag[2][512];              // [(slice*2+hi)*32+q] 16B frags, dbuf
    __shared__ uint4 Qlo[1024];                  // [(sl*2+hi)*32+q] Q-lo frags
    __shared__ float mbuf[2][4][32];
    __shared__ float lbuf[2][4][32];

    // Q-hi fragments resident in registers
    f16x8 qhf[16];
    #pragma unroll
    for (int sl = 0; sl < 16; ++sl)
        qhf[sl] = *(const f16x8*)(qhb + (size_t)(q0 + col) * DIM + sl * 16 + 8 * hi);

    // wave 0 fills Q-lo frags (conflict-free b128 writes)
    if (wid == 0) {
        #pragma unroll
        for (int sl = 0; sl < 16; ++sl) {
            const f16x8 d = *(const f16x8*)(qlb + (size_t)(q0 + col) * DIM + sl * 16 + 8 * hi);
            Qlo[(sl * 2 + hi) * 32 + col] = __builtin_bit_cast(uint4, d);
        }
    }
    __syncthreads();

    float m_run = -1e30f, l_run = 0.f;
    f32x16 oacc[2] = {};                         // cols 64*wid+col, 64*wid+32+col

    for (int it = 0; it < niter; ++it) {
        const int j0 = it << 7;
        const int nk = min(128, qend - j0);
        const int pb = it & 1;
        const int nslice = nk >> 4;              // 16-key PV slices this iter
        const int jw = j0 + 32 * wid;
        const bool active = 32 * wid < nk;

        // ---- QK^T (wave-local 32 keys) ----
        float sv[16];
        float pmax = -1e30f, tsum = 0.f;
        if (active) {
            const f16* kb = khb + (size_t)(jw + col) * DIM + 8 * hi;
            f32x16 s1 = {}, s2 = {};
            #pragma unroll
            for (int sl = 0; sl < 16; ++sl) {
                const f16x8 kf = *(const f16x8*)(kb + sl * 16);
                const f16x8 qlo = __builtin_bit_cast(f16x8, Qlo[(sl * 2 + hi) * 32 + col]);
                s1 = __builtin_amdgcn_mfma_f32_32x32x16_f16(kf, qhf[sl], s1, 0, 0, 0);
                s2 = __builtin_amdgcn_mfma_f32_32x32x16_f16(kf, qlo, s2, 0, 0, 0);
            }
            #pragma unroll
            for (int r = 0; r < 16; ++r) {
                const int kg = jw + (r & 3) + 8 * (r >> 2) + 4 * hi;
                const float x = (kg <= q0 + col) ? (s1[r] + s2[r]) : -1e30f;
                sv[r] = x;
                pmax = fmaxf(pmax, x);
            }
            pmax = fmaxf(pmax, __shfl_xor(pmax, 32));
        }

        // ---- V prefetch (consumed after the barrier -> latency hidden) ----
        f16x8 vf0[8], vf1[8];
        const f16* vb0 = vTb + (size_t)(64 * wid + col) * SEQ + j0 + 8 * hi;
        const f16* vb1 = vb0 + (size_t)32 * SEQ;
        #pragma unroll
        for (int s = 0; s < 8; ++s) {
            if (s < nslice) {
                vf0[s] = *(const f16x8*)(vb0 + 16 * s);
                vf1[s] = *(const f16x8*)(vb1 + 16 * s);
            }
        }

        // ---- local softmax + A-frag build + P store ----
        if (active) {
            float p[16];
            #pragma unroll
            for (int r = 0; r < 16; ++r) {
                p[r] = exp2f(sv[r] - pmax);
                tsum += p[r];
            }
            tsum += __shfl_xor(tsum, 32);
            uint32_t Wd[8], Od[8];
            #pragma unroll
            for (int jj = 0; jj < 8; ++jj)
                Wd[jj] = __builtin_bit_cast(uint32_t,
                    __builtin_amdgcn_cvt_pkrtz(p[2 * jj], p[2 * jj + 1]));
            #pragma unroll
            for (int jj = 0; jj < 8; ++jj)
                Od[jj] = (uint32_t)__shfl_xor((int)Wd[jj], 32);
            uint4 A0, A1;
            if (hi == 0) {
                A0.x = Wd[0]; A0.y = Wd[1]; A0.z = Od[0]; A0.w = Od[1];
                A1.x = Wd[4]; A1.y = Wd[5]; A1.z = Od[4]; A1.w = Od[5];
            } else {
                A0.x = Od[2]; A0.y = Od[3]; A0.z = Wd[2]; A0.w = Wd[3];
                A1.x = Od[6]; A1.y = Od[7]; A1.z = Wd[6]; A1.w = Wd[7];
            }
            Pfrag[pb][(4 * wid + hi) * 32 + col]     = A0;   // slice 2*wid
            Pfrag[pb][(4 * wid + 2 + hi) * 32 + col] = A1;   // slice 2*wid+1
        }
        if (lane < 32) {
            mbuf[pb][wid][col] = pmax;
            lbuf[pb][wid][col] = tsum;
        }
        __syncthreads();                         // the ONLY barrier per iter

        // ---- merge m/l, defer-max rescale, correction factors ----
        const float m0 = mbuf[pb][0][col], m1 = mbuf[pb][1][col];
        const float m2 = mbuf[pb][2][col], m3 = mbuf[pb][3][col];
        const float mt = fmaxf(fmaxf(m0, m1), fmaxf(m2, m3));
        float scale = 1.f;
        if (__any(mt > m_run + 11.5415603f)) {   // 8 nats in log2 units
            const float m_new = fmaxf(m_run, mt);
            scale = exp2f(m_run - m_new);
            m_run = m_new;
            #pragma unroll
            for (int r = 0; r < 16; ++r) {
                const int qr = (r & 3) + 8 * (r >> 2) + 4 * hi;
                const float scr = __shfl(scale, qr | (lane & 32));
                oacc[0][r] *= scr;
                oacc[1][r] *= scr;
            }
        }
        const float c0 = exp2f(m0 - m_run), c1 = exp2f(m1 - m_run);
        const float c2 = exp2f(m2 - m_run), c3 = exp2f(m3 - m_run);
        l_run = l_run * scale + lbuf[pb][0][col] * c0 + lbuf[pb][1][col] * c1
                              + lbuf[pb][2][col] * c2 + lbuf[pb][3][col] * c3;
        const f16 ch[4] = {(f16)c0, (f16)c1, (f16)c2, (f16)c3};

        // ---- PV (own 64-col quarter, all slices) ----
        #pragma unroll
        for (int s = 0; s < 8; ++s) {
            if (s < nslice) {
                f16x8 af = __builtin_bit_cast(f16x8, Pfrag[pb][(2 * s + hi) * 32 + col]);
                af = af * ch[s >> 1];            // producer-wave correction
                oacc[0] = __builtin_amdgcn_mfma_f32_32x32x16_f16(af, vf0[s], oacc[0], 0, 0, 0);
                oacc[1] = __builtin_amdgcn_mfma_f32_32x32x16_f16(af, vf1[s], oacc[1], 0, 0, 0);
            }
        }
    }

    // epilogue: divide by l, store fp32
    const float linv = 1.f / l_run;
    #pragma unroll
    for (int r = 0; r < 16; ++r) {
        const int qr = (r & 3) + 8 * (r >> 2) + 4 * hi;
        const float lr = __shfl(linv, qr | (lane & 32));
        const int n = q0 + qr;
        outb[(size_t)n * DIM + 64 * wid + col]      = oacc[0][r] * lr;
        outb[(size_t)n * DIM + 64 * wid + 32 + col] = oacc[1][r] * lr;
    }
}

// ---------------------------------------------------------------------------
extern "C" void kernel_launch(void* const* d_in, const int* in_sizes, int n_in,
                              void* d_out, int out_size, void* d_ws, size_t ws_size,
                              hipStream_t stream) {
    const float* x  = (const float*)d_in[0];
    const float* Wq = (const float*)d_in[1];
    const float* bq = (const float*)d_in[2];
    const float* Wk = (const float*)d_in[3];
    const float* bk = (const float*)d_in[4];
    const float* Wv = (const float*)d_in[5];
    const float* bv = (const float*)d_in[6];
    float* out = (float*)d_out;

    const size_t PP = (size_t)SEQ * DIM;            // per-batch plane elems
    const size_t FULL = 4 * PP;                     // all-batch plane elems

    if (ws_size >= FULL * 2 * 5) {
        // full-batch path: 5 fp16 planes of 8.4MB
        f16* qh = (f16*)d_ws;
        f16* ql = qh + FULL;
        f16* kh = ql + FULL;
        f16* vv = kh + FULL;
        f16* vT = vv + FULL;
        proj_mfma<<<dim3(256), 256, 0, stream>>>(x, Wq, bq, qh, ql, LOG2E);
        proj_mfma<<<dim3(256), 256, 0, stream>>>(x, Wk, bk, kh, nullptr, 1.f);
        proj_mfma<<<dim3(256), 256, 0, stream>>>(x, Wv, bv, vv, nullptr, 1.f);
        transpose_v<<<dim3(128, 8, 4), dim3(32, 8), 0, stream>>>(vv, vT);
        attn_flash<<<dim3(512), 256, 0, stream>>>(qh, ql, kh, vT, out, 4);
    } else {
        // per-batch fallback (10.5 MB of ws)
        f16* qh = (f16*)d_ws;
        f16* ql = qh + PP;
        f16* kh = ql + PP;
        f16* vv = kh + PP;
        f16* vT = vv + PP;
        for (int b = 0; b < 4; ++b) {
            const float* xb = x + b * PP;
            proj_mfma<<<dim3(64), 256, 0, stream>>>(xb, Wq, bq, qh, ql, LOG2E);
            proj_mfma<<<dim3(64), 256, 0, stream>>>(xb, Wk, bk, kh, nullptr, 1.f);
            proj_mfma<<<dim3(64), 256, 0, stream>>>(xb, Wv, bv, vv, nullptr, 1.f);
            transpose_v<<<dim3(128, 8, 1), dim3(32, 8), 0, stream>>>(vv, vT);
            attn_flash<<<dim3(128), 256, 0, stream>>>(qh, ql, kh, vT, out + b * PP, 1);
        }
    }
}